// Round 3
// baseline (4405.671 us; speedup 1.0000x reference)
//
#include <hip/hip_runtime.h>
#include <math.h>

#define D_MODEL 2048
#define CONV_DIM 6144
#define N_HEADS 32
#define LSEQ 4096
#define NROWS 8192           // B*L
#define NCHUNK 64
#define RMS_EPS 1.1920929e-07f

__device__ __forceinline__ float silu(float v) { return v / (1.f + expf(-v)); }

// ---------------------------------------------------------------------------
// NT GEMM: C[m,n] = sum_k A[m,k] * B[n,k].  A: MxK row-major, B: NxK row-major.
// Output split at column nsplit: cols [0,nsplit) -> C0 (ld ldc0),
// cols [nsplit,N) -> C1 (ld ldc1, col-nsplit).  128x128x16 tile, 8x8/thread.
// ---------------------------------------------------------------------------
__global__ __launch_bounds__(256) void gemm_nt(
    const float* __restrict__ A, const float* __restrict__ B,
    float* __restrict__ C0, float* __restrict__ C1,
    int M, int N, int K, int nsplit, int ldc0, int ldc1)
{
    const int BK = 16;
    __shared__ float As[16][128];
    __shared__ float Bs[16][128];

    int m0 = blockIdx.y * 128;
    int n0 = blockIdx.x * 128;
    int tid = threadIdx.x;

    int lrow = tid >> 1;           // 0..127
    int lk   = (tid & 1) * 8;      // 0 or 8
    const float* Aptr = A + (size_t)(m0 + lrow) * K + lk;
    const float* Bptr = B + (size_t)(n0 + lrow) * K + lk;

    int tx = tid & 15;             // n dimension
    int ty = tid >> 4;             // m dimension

    float acc[8][8];
    #pragma unroll
    for (int i = 0; i < 8; i++)
        #pragma unroll
        for (int j = 0; j < 8; j++) acc[i][j] = 0.f;

    float4 a0 = *(const float4*)(Aptr);
    float4 a1 = *(const float4*)(Aptr + 4);
    float4 b0 = *(const float4*)(Bptr);
    float4 b1 = *(const float4*)(Bptr + 4);

    for (int k0 = 0; k0 < K; k0 += BK) {
        __syncthreads();
        As[lk + 0][lrow] = a0.x; As[lk + 1][lrow] = a0.y;
        As[lk + 2][lrow] = a0.z; As[lk + 3][lrow] = a0.w;
        As[lk + 4][lrow] = a1.x; As[lk + 5][lrow] = a1.y;
        As[lk + 6][lrow] = a1.z; As[lk + 7][lrow] = a1.w;
        Bs[lk + 0][lrow] = b0.x; Bs[lk + 1][lrow] = b0.y;
        Bs[lk + 2][lrow] = b0.z; Bs[lk + 3][lrow] = b0.w;
        Bs[lk + 4][lrow] = b1.x; Bs[lk + 5][lrow] = b1.y;
        Bs[lk + 6][lrow] = b1.z; Bs[lk + 7][lrow] = b1.w;
        __syncthreads();
        if (k0 + BK < K) {          // prefetch next tile
            a0 = *(const float4*)(Aptr + k0 + BK);
            a1 = *(const float4*)(Aptr + k0 + BK + 4);
            b0 = *(const float4*)(Bptr + k0 + BK);
            b1 = *(const float4*)(Bptr + k0 + BK + 4);
        }
        #pragma unroll
        for (int kk = 0; kk < BK; ++kk) {
            float ar[8], br[8];
            *(float4*)&ar[0] = *(const float4*)&As[kk][ty * 4];
            *(float4*)&ar[4] = *(const float4*)&As[kk][ty * 4 + 64];
            *(float4*)&br[0] = *(const float4*)&Bs[kk][tx * 4];
            *(float4*)&br[4] = *(const float4*)&Bs[kk][tx * 4 + 64];
            #pragma unroll
            for (int i = 0; i < 8; i++)
                #pragma unroll
                for (int j = 0; j < 8; j++)
                    acc[i][j] = fmaf(ar[i], br[j], acc[i][j]);
        }
    }

    #pragma unroll
    for (int i = 0; i < 8; i++) {
        int row = m0 + ty * 4 + (i & 3) + (i >> 2) * 64;
        #pragma unroll
        for (int jb = 0; jb < 2; jb++) {
            int col = n0 + tx * 4 + jb * 64;
            float4 o = make_float4(acc[i][jb * 4 + 0], acc[i][jb * 4 + 1],
                                   acc[i][jb * 4 + 2], acc[i][jb * 4 + 3]);
            if (col < nsplit) *(float4*)&C0[(size_t)row * ldc0 + col] = o;
            else              *(float4*)&C1[(size_t)row * ldc1 + (col - nsplit)] = o;
        }
    }
}

// ---------------------------------------------------------------------------
// chunk_states with conv+silu fused (reads PRE-conv xraw).
// cs[((b*32+h)*64+c)*64+n] = sum_l silu(conv(x))[l,n] * silu(conv(B))[l,n]
// grid: 4096 blocks ((b*32+h)*64+c), 64 threads (n).
// ---------------------------------------------------------------------------
__global__ __launch_bounds__(64) void cs_conv(
    const float* __restrict__ xraw, const float* __restrict__ cw,
    const float* __restrict__ cb, float* __restrict__ cs)
{
    const int CD = CONV_DIM;
    int blk = blockIdx.x;
    int c = blk & 63; int h = (blk >> 6) & 31; int b = blk >> 11;
    int n = threadIdx.x;
    int colx = h * 64 + n;
    int colB = D_MODEL + colx;
    const float* px = xraw + ((size_t)(b * LSEQ + c * 64)) * CD + colx;
    const float* pB = px + D_MODEL;
    float wx0 = cw[colx * 3], wx1 = cw[colx * 3 + 1], wx2 = cw[colx * 3 + 2], bx = cb[colx];
    float wb0 = cw[colB * 3], wb1 = cw[colB * 3 + 1], wb2 = cw[colB * 3 + 2], bb = cb[colB];

    float xm = (c > 0) ? px[-CD] : 0.f;
    float Bm = (c > 0) ? pB[-CD] : 0.f;
    float x0 = px[0], B0 = pB[0];
    float s = 0.f;
    for (int l = 0; l < 64; l++) {
        bool hasp = (c * 64 + l) < (LSEQ - 1);
        float xp = hasp ? px[(size_t)(l + 1) * CD] : 0.f;
        float Bp = hasp ? pB[(size_t)(l + 1) * CD] : 0.f;
        float vx = fmaf(wx0, xm, fmaf(wx1, x0, fmaf(wx2, xp, bx)));
        float vB = fmaf(wb0, Bm, fmaf(wb1, B0, fmaf(wb2, Bp, bb)));
        vx = silu(vx); vB = silu(vB);
        s = fmaf(vx, vB, s);
        xm = x0; x0 = xp; Bm = B0; B0 = Bp;
    }
    cs[(size_t)blk * 64 + n] = s;
}

// ---------------------------------------------------------------------------
// Sequential chunk scan.  decay = exp(63*A_log[h]) (A constant per head).
// prev[bh,c,n] = state BEFORE chunk c.  grid: 64 blocks (b*32+h), 64 threads.
// ---------------------------------------------------------------------------
__global__ void scan_kernel(const float* __restrict__ cs,
                            const float* __restrict__ A_log,
                            float* __restrict__ prev)
{
    int bh = blockIdx.x;
    int h = bh & 31;
    int n = threadIdx.x;
    float d = expf(63.f * A_log[h]);
    float st = 0.f;
    for (int c = 0; c < NCHUNK; c++) {
        size_t i = ((size_t)bh * 64 + c) * 64 + n;
        prev[i] = st;
        st = fmaf(st, d, cs[i]);
    }
}

// ---------------------------------------------------------------------------
// Per (b,h,chunk): conv+silu on the fly into LDS, then
// G = tril(C B^T); Y = G x + (prev . C[l]) broadcast over p.  256 threads.
// ---------------------------------------------------------------------------
__global__ __launch_bounds__(256) void ssd_y(
    const float* __restrict__ xraw, const float* __restrict__ cw,
    const float* __restrict__ cb, const float* __restrict__ prev,
    float* __restrict__ yraw)
{
    const int CD = CONV_DIM;
    __shared__ float Cs[64][65];
    __shared__ float Bs[64][65];      // holds B, then reused for G
    __shared__ float xs[64][64];
    __shared__ float pv[64];
    __shared__ float off[64];
    __shared__ float w0s[192], w1s[192], w2s[192], bss[192];

    int blk = blockIdx.x;
    int c = blk & 63; int h = (blk >> 6) & 31; int b = blk >> 11;
    int tid = threadIdx.x;

    if (tid < 192) {                         // conv weights for this head's cols
        int g = tid >> 6, n = tid & 63;
        int col = g * D_MODEL + h * 64 + n;
        w0s[tid] = cw[col * 3]; w1s[tid] = cw[col * 3 + 1]; w2s[tid] = cw[col * 3 + 2];
        bss[tid] = cb[col];
    }
    if (tid < 64) pv[tid] = prev[((size_t)(b * 32 + h) * 64 + c) * 64 + tid];
    __syncthreads();

    size_t rowbase = ((size_t)(b * LSEQ + c * 64)) * CD;
    #pragma unroll
    for (int j = 0; j < 4; j++) {
        int idx = tid + 256 * j;          // 0..1023
        int r = idx >> 4;
        int c4 = (idx & 15) * 4;
        bool hasm = (c > 0) || (r > 0);
        bool hasp = (c * 64 + r) < (LSEQ - 1);
        const float* p0 = xraw + rowbase + (size_t)r * CD + h * 64 + c4;
        #pragma unroll
        for (int g = 0; g < 3; g++) {
            const float* pg = p0 + g * D_MODEL;
            float4 rm = hasm ? *(const float4*)(pg - CD) : make_float4(0, 0, 0, 0);
            float4 r0 = *(const float4*)(pg);
            float4 rp = hasp ? *(const float4*)(pg + CD) : make_float4(0, 0, 0, 0);
            int wi = g * 64 + c4;
            float4 o;
            o.x = silu(fmaf(w0s[wi + 0], rm.x, fmaf(w1s[wi + 0], r0.x, fmaf(w2s[wi + 0], rp.x, bss[wi + 0]))));
            o.y = silu(fmaf(w0s[wi + 1], rm.y, fmaf(w1s[wi + 1], r0.y, fmaf(w2s[wi + 1], rp.y, bss[wi + 1]))));
            o.z = silu(fmaf(w0s[wi + 2], rm.z, fmaf(w1s[wi + 2], r0.z, fmaf(w2s[wi + 2], rp.z, bss[wi + 2]))));
            o.w = silu(fmaf(w0s[wi + 3], rm.w, fmaf(w1s[wi + 3], r0.w, fmaf(w2s[wi + 3], rp.w, bss[wi + 3]))));
            if (g == 0)      { *(float4*)&xs[r][c4] = o; }
            else if (g == 1) { Bs[r][c4] = o.x; Bs[r][c4+1] = o.y; Bs[r][c4+2] = o.z; Bs[r][c4+3] = o.w; }
            else             { Cs[r][c4] = o.x; Cs[r][c4+1] = o.y; Cs[r][c4+2] = o.z; Cs[r][c4+3] = o.w; }
        }
    }
    __syncthreads();

    // stage 1: G[l,m] (4x4 per thread) + off[l]
    int lb = tid >> 4;         // rows lb*4..+3
    int mb = tid & 15;         // cols mb*4..+3
    float g4[4][4];
    #pragma unroll
    for (int i = 0; i < 4; i++)
        #pragma unroll
        for (int j = 0; j < 4; j++) g4[i][j] = 0.f;
    for (int n = 0; n < 64; n++) {
        float cr[4], br[4];
        #pragma unroll
        for (int i = 0; i < 4; i++) cr[i] = Cs[lb * 4 + i][n];
        #pragma unroll
        for (int j = 0; j < 4; j++) br[j] = Bs[mb * 4 + j][n];
        #pragma unroll
        for (int i = 0; i < 4; i++)
            #pragma unroll
            for (int j = 0; j < 4; j++) g4[i][j] = fmaf(cr[i], br[j], g4[i][j]);
    }
    if (tid < 64) {
        float o = 0.f;
        for (int n = 0; n < 64; n++) o = fmaf(pv[n], Cs[tid][n], o);
        off[tid] = o;
    }
    __syncthreads();   // everyone done reading Bs
    #pragma unroll
    for (int i = 0; i < 4; i++)
        #pragma unroll
        for (int j = 0; j < 4; j++) {
            int l = lb * 4 + i, m = mb * 4 + j;
            Bs[l][m] = (m <= l) ? g4[i][j] : 0.f;   // G (causal) into Bs
        }
    __syncthreads();

    // stage 2: Y[l, pb..pb+15] = sum_m G[l,m]*x[m,p] + off[l]
    int l = tid >> 2;
    int pb = (tid & 3) * 16;
    float acc[16];
    float ofl = off[l];
    #pragma unroll
    for (int i = 0; i < 16; i++) acc[i] = ofl;
    int mmax = l | 3;                    // G zero beyond within 4-block
    for (int m = 0; m <= mmax; m++) {
        float gv = Bs[l][m];
        float4 x0 = *(const float4*)&xs[m][pb];
        float4 x1 = *(const float4*)&xs[m][pb + 4];
        float4 x2 = *(const float4*)&xs[m][pb + 8];
        float4 x3 = *(const float4*)&xs[m][pb + 12];
        acc[0]  = fmaf(gv, x0.x, acc[0]);  acc[1]  = fmaf(gv, x0.y, acc[1]);
        acc[2]  = fmaf(gv, x0.z, acc[2]);  acc[3]  = fmaf(gv, x0.w, acc[3]);
        acc[4]  = fmaf(gv, x1.x, acc[4]);  acc[5]  = fmaf(gv, x1.y, acc[5]);
        acc[6]  = fmaf(gv, x1.z, acc[6]);  acc[7]  = fmaf(gv, x1.w, acc[7]);
        acc[8]  = fmaf(gv, x2.x, acc[8]);  acc[9]  = fmaf(gv, x2.y, acc[9]);
        acc[10] = fmaf(gv, x2.z, acc[10]); acc[11] = fmaf(gv, x2.w, acc[11]);
        acc[12] = fmaf(gv, x3.x, acc[12]); acc[13] = fmaf(gv, x3.y, acc[13]);
        acc[14] = fmaf(gv, x3.z, acc[14]); acc[15] = fmaf(gv, x3.w, acc[15]);
    }
    float* dst = yraw + ((size_t)(b * LSEQ + c * 64 + l)) * D_MODEL + h * 64 + pb;
    #pragma unroll
    for (int q = 0; q < 4; q++)
        *(float4*)(dst + q * 4) = make_float4(acc[q * 4], acc[q * 4 + 1],
                                              acc[q * 4 + 2], acc[q * 4 + 3]);
}

// ---------------------------------------------------------------------------
// y = y*silu(z); y *= rsqrt(mean(y^2)+eps)*rms_w.  In-place over ybuf.
// ---------------------------------------------------------------------------
__global__ __launch_bounds__(256) void gate_rms(
    float* __restrict__ ybuf, const float* __restrict__ zbuf,
    const float* __restrict__ rms_w)
{
    int row = blockIdx.x;
    float* yp = ybuf + (size_t)row * D_MODEL;
    const float* zp = zbuf + (size_t)row * D_MODEL;
    float v[8];
    float ss = 0.f;
    #pragma unroll
    for (int j = 0; j < 8; j++) {
        int col = threadIdx.x + 256 * j;
        float y = yp[col];
        float z = zp[col];
        float gv = y * silu(z);
        v[j] = gv;
        ss = fmaf(gv, gv, ss);
    }
    #pragma unroll
    for (int o = 32; o > 0; o >>= 1) ss += __shfl_xor(ss, o);
    __shared__ float red[4];
    int wid = threadIdx.x >> 6;
    if ((threadIdx.x & 63) == 0) red[wid] = ss;
    __syncthreads();
    float tot = red[0] + red[1] + red[2] + red[3];
    float scale = rsqrtf(tot * (1.f / D_MODEL) + RMS_EPS);
    #pragma unroll
    for (int j = 0; j < 8; j++) {
        int col = threadIdx.x + 256 * j;
        yp[col] = v[j] * scale * rms_w[col];
    }
}

// ---------------------------------------------------------------------------
extern "C" void kernel_launch(void* const* d_in, const int* in_sizes, int n_in,
                              void* d_out, int out_size, void* d_ws, size_t ws_size,
                              hipStream_t stream)
{
    const float* u      = (const float*)d_in[0];
    const float* W_in   = (const float*)d_in[1];
    const float* W_out  = (const float*)d_in[2];
    const float* conv_w = (const float*)d_in[3];
    const float* conv_b = (const float*)d_in[4];
    const float* A_log  = (const float*)d_in[5];
    const float* rms_w  = (const float*)d_in[6];
    float* out = (float*)d_out;

    // workspace (floats): xraw 50.3M | ybuf 16.8M | cs 0.26M | prev 0.26M
    // total = 67,633,152 floats = 258 MB.  z lives in d_out until gemm2.
    float* xraw  = (float*)d_ws;
    float* ybuf  = xraw + (size_t)NROWS * CONV_DIM;
    float* csbuf = ybuf + (size_t)NROWS * D_MODEL;
    float* prevb = csbuf + 262144;
    float* zbuf  = out;                       // cols 0..2047 of gemm1

    // 1) zxbcdt = u @ W_in^T (skip unused dt cols); z -> d_out, xBC -> xraw
    gemm_nt<<<dim3(64, 64), 256, 0, stream>>>(u, W_in, zbuf, xraw,
                                              NROWS, 8192, D_MODEL,
                                              D_MODEL, D_MODEL, CONV_DIM);
    // 2) chunk states (conv fused)
    cs_conv<<<dim3(4096), 64, 0, stream>>>(xraw, conv_w, conv_b, csbuf);
    // 3) inter-chunk scan
    scan_kernel<<<dim3(64), 64, 0, stream>>>(csbuf, A_log, prevb);
    // 4) per-chunk Y (conv fused)
    ssd_y<<<dim3(4096), 256, 0, stream>>>(xraw, conv_w, conv_b, prevb, ybuf);
    // 5) gate + RMSNorm (in-place on ybuf; z read from d_out)
    gate_rms<<<dim3(NROWS), 256, 0, stream>>>(ybuf, zbuf, rms_w);
    // 6) out = ynorm @ W_out^T (overwrites z in d_out)
    gemm_nt<<<dim3(16, 64), 256, 0, stream>>>(ybuf, W_out, out, out,
                                              NROWS, D_MODEL, D_MODEL,
                                              D_MODEL, D_MODEL, D_MODEL);
}

// Round 4
// 845.557 us; speedup vs baseline: 5.2104x; 5.2104x over previous
//
#include <hip/hip_runtime.h>
#include <math.h>

#define D_MODEL 2048
#define CONV_DIM 6144
#define N_HEADS 32
#define LSEQ 4096
#define NROWS 8192           // B*L
#define NCHUNK 64
#define RMS_EPS 1.1920929e-07f

typedef _Float16 half8 __attribute__((ext_vector_type(8)));
typedef float f32x4 __attribute__((ext_vector_type(4)));

__device__ __forceinline__ float silu(float v) { return v / (1.f + expf(-v)); }

__device__ __forceinline__ void glds16(const void* g, void* l) {
    __builtin_amdgcn_global_load_lds((const __attribute__((address_space(1))) void*)g,
                                     (__attribute__((address_space(3))) void*)l,
                                     16, 0, 0);
}

// ---------------------------------------------------------------------------
// fp32 -> fp16 cast, 8 elements/thread.
// ---------------------------------------------------------------------------
__global__ __launch_bounds__(256) void cvt_f16(
    const float* __restrict__ src, _Float16* __restrict__ dst)
{
    size_t i = ((size_t)blockIdx.x * 256 + threadIdx.x) * 8;
    float4 f0 = *(const float4*)(src + i);
    float4 f1 = *(const float4*)(src + i + 4);
    half8 h;
    h[0] = (_Float16)f0.x; h[1] = (_Float16)f0.y;
    h[2] = (_Float16)f0.z; h[3] = (_Float16)f0.w;
    h[4] = (_Float16)f1.x; h[5] = (_Float16)f1.y;
    h[6] = (_Float16)f1.z; h[7] = (_Float16)f1.w;
    *(half8*)(dst + i) = h;
}

// ---------------------------------------------------------------------------
// fp16 NT MFMA GEMM: C[m,n] = sum_k A[m,k]*B[n,k].  A: MxK, B: NxK row-major.
// 128x128 tile, BK=32, 4 waves, 16x16x32 MFMA, global_load_lds staging.
// LDS layout [128 rows][32 k] fp16 with 16B-slot XOR swizzle:
//   phys_k16 = logical_k16 ^ ((row>>1)&3)   (applied on BOTH write & read)
// Output cols < nsplit -> C0 (ld ldc0), else C1 (ld ldc1, col-nsplit).
// ---------------------------------------------------------------------------
__global__ __launch_bounds__(256) void gemm_f16(
    const _Float16* __restrict__ A, const _Float16* __restrict__ B,
    float* __restrict__ C0, float* __restrict__ C1,
    int M, int N, int K, int nsplit, int ldc0, int ldc1)
{
    __shared__ __align__(16) _Float16 Al[4096];   // 8 KB
    __shared__ __align__(16) _Float16 Bl[4096];   // 8 KB

    const int tid  = threadIdx.x;
    const int wave = tid >> 6;
    const int lane = tid & 63;
    const int m0 = blockIdx.y * 128;
    const int n0 = blockIdx.x * 128;

    // --- staging: 8 segs of 16 rows; wave w owns segs {2w, 2w+1} per operand.
    // seg s, lane l -> slot P = s*64+l: row r = s*16+(l>>2), phys k16 = l&3;
    // the global source supplies the LOGICAL k16 = phys ^ ((r>>1)&3).
    const int s0 = wave * 2, s1 = s0 + 1;
    const int r0 = s0 * 16 + (lane >> 2);
    const int r1 = s1 * 16 + (lane >> 2);
    const int lk0 = ((lane & 3) ^ ((r0 >> 1) & 3)) * 8;   // element offset in row
    const int lk1 = ((lane & 3) ^ ((r1 >> 1) & 3)) * 8;
    const _Float16* gA0 = A + (size_t)(m0 + r0) * K + lk0;
    const _Float16* gA1 = A + (size_t)(m0 + r1) * K + lk1;
    const _Float16* gB0 = B + (size_t)(n0 + r0) * K + lk0;
    const _Float16* gB1 = B + (size_t)(n0 + r1) * K + lk1;
    _Float16* lA0 = Al + s0 * 512;    // 512 halfs = 1 KB per wave-instruction
    _Float16* lA1 = Al + s1 * 512;
    _Float16* lB0 = Bl + s0 * 512;
    _Float16* lB1 = Bl + s1 * 512;

    // --- fragment ds_read byte offsets (constant per thread).
    // A-frag: row = wr + t*16 + (lane&15), k16 = lane>>4 (swizzled).
    const int wr = (wave >> 1) * 64;
    const int wc = (wave & 1) * 64;
    int offA[4], offB[4];
    #pragma unroll
    for (int t = 0; t < 4; t++) {
        int ra = wr + t * 16 + (lane & 15);
        offA[t] = ra * 64 + ((((lane >> 4) ^ ((ra >> 1) & 3))) << 4);
        int rb = wc + t * 16 + (lane & 15);
        offB[t] = rb * 64 + ((((lane >> 4) ^ ((rb >> 1) & 3))) << 4);
    }

    f32x4 acc[4][4];
    #pragma unroll
    for (int i = 0; i < 4; i++)
        #pragma unroll
        for (int j = 0; j < 4; j++) acc[i][j] = (f32x4)0.f;

    for (int k0 = 0; k0 < K; k0 += 32) {
        __syncthreads();                       // prev iter's LDS reads done
        glds16(gA0, lA0); glds16(gA1, lA1);
        glds16(gB0, lB0); glds16(gB1, lB1);
        gA0 += 32; gA1 += 32; gB0 += 32; gB1 += 32;
        __syncthreads();                       // staging visible (vmcnt drain)

        half8 af[4], bf[4];
        #pragma unroll
        for (int t = 0; t < 4; t++) {
            af[t] = *(const half8*)((const char*)Al + offA[t]);
            bf[t] = *(const half8*)((const char*)Bl + offB[t]);
        }
        #pragma unroll
        for (int mt = 0; mt < 4; mt++)
            #pragma unroll
            for (int nt = 0; nt < 4; nt++)
                acc[mt][nt] = __builtin_amdgcn_mfma_f32_16x16x32_f16(
                    af[mt], bf[nt], acc[mt][nt], 0, 0, 0);
    }

    // --- epilogue: D lane mapping col=lane&15, row=(lane>>4)*4+j
    const int crow = (lane >> 4) * 4;
    const int ccol = lane & 15;
    #pragma unroll
    for (int mt = 0; mt < 4; mt++) {
        #pragma unroll
        for (int nt = 0; nt < 4; nt++) {
            int col = n0 + wc + nt * 16 + ccol;
            int rowb = m0 + wr + mt * 16 + crow;
            #pragma unroll
            for (int j = 0; j < 4; j++) {
                float v = acc[mt][nt][j];
                if (col < nsplit) C0[(size_t)(rowb + j) * ldc0 + col] = v;
                else              C1[(size_t)(rowb + j) * ldc1 + (col - nsplit)] = v;
            }
        }
    }
}

// ---------------------------------------------------------------------------
// chunk_states with conv+silu fused (reads PRE-conv xraw).
// ---------------------------------------------------------------------------
__global__ __launch_bounds__(64) void cs_conv(
    const float* __restrict__ xraw, const float* __restrict__ cw,
    const float* __restrict__ cb, float* __restrict__ cs)
{
    const int CD = CONV_DIM;
    int blk = blockIdx.x;
    int c = blk & 63; int h = (blk >> 6) & 31; int b = blk >> 11;
    int n = threadIdx.x;
    int colx = h * 64 + n;
    int colB = D_MODEL + colx;
    const float* px = xraw + ((size_t)(b * LSEQ + c * 64)) * CD + colx;
    const float* pB = px + D_MODEL;
    float wx0 = cw[colx * 3], wx1 = cw[colx * 3 + 1], wx2 = cw[colx * 3 + 2], bx = cb[colx];
    float wb0 = cw[colB * 3], wb1 = cw[colB * 3 + 1], wb2 = cw[colB * 3 + 2], bb = cb[colB];

    float xm = (c > 0) ? px[-CD] : 0.f;
    float Bm = (c > 0) ? pB[-CD] : 0.f;
    float x0 = px[0], B0 = pB[0];
    float s = 0.f;
    for (int l = 0; l < 64; l++) {
        bool hasp = (c * 64 + l) < (LSEQ - 1);
        float xp = hasp ? px[(size_t)(l + 1) * CD] : 0.f;
        float Bp = hasp ? pB[(size_t)(l + 1) * CD] : 0.f;
        float vx = fmaf(wx0, xm, fmaf(wx1, x0, fmaf(wx2, xp, bx)));
        float vB = fmaf(wb0, Bm, fmaf(wb1, B0, fmaf(wb2, Bp, bb)));
        vx = silu(vx); vB = silu(vB);
        s = fmaf(vx, vB, s);
        xm = x0; x0 = xp; Bm = B0; B0 = Bp;
    }
    cs[(size_t)blk * 64 + n] = s;
}

// ---------------------------------------------------------------------------
// Sequential chunk scan.  decay = exp(63*A_log[h]).
// ---------------------------------------------------------------------------
__global__ void scan_kernel(const float* __restrict__ cs,
                            const float* __restrict__ A_log,
                            float* __restrict__ prev)
{
    int bh = blockIdx.x;
    int h = bh & 31;
    int n = threadIdx.x;
    float d = expf(63.f * A_log[h]);
    float st = 0.f;
    for (int c = 0; c < NCHUNK; c++) {
        size_t i = ((size_t)bh * 64 + c) * 64 + n;
        prev[i] = st;
        st = fmaf(st, d, cs[i]);
    }
}

// ---------------------------------------------------------------------------
// Per (b,h,chunk): conv+silu on the fly into LDS, then
// G = tril(C B^T); Y = G x + (prev . C[l]) broadcast over p.  256 threads.
// ---------------------------------------------------------------------------
__global__ __launch_bounds__(256) void ssd_y(
    const float* __restrict__ xraw, const float* __restrict__ cw,
    const float* __restrict__ cb, const float* __restrict__ prev,
    float* __restrict__ yraw)
{
    const int CD = CONV_DIM;
    __shared__ float Cs[64][65];
    __shared__ float Bs[64][65];      // holds B, then reused for G
    __shared__ float xs[64][64];
    __shared__ float pv[64];
    __shared__ float off[64];
    __shared__ float w0s[192], w1s[192], w2s[192], bss[192];

    int blk = blockIdx.x;
    int c = blk & 63; int h = (blk >> 6) & 31; int b = blk >> 11;
    int tid = threadIdx.x;

    if (tid < 192) {
        int g = tid >> 6, n = tid & 63;
        int col = g * D_MODEL + h * 64 + n;
        w0s[tid] = cw[col * 3]; w1s[tid] = cw[col * 3 + 1]; w2s[tid] = cw[col * 3 + 2];
        bss[tid] = cb[col];
    }
    if (tid < 64) pv[tid] = prev[((size_t)(b * 32 + h) * 64 + c) * 64 + tid];
    __syncthreads();

    size_t rowbase = ((size_t)(b * LSEQ + c * 64)) * CD;
    #pragma unroll
    for (int j = 0; j < 4; j++) {
        int idx = tid + 256 * j;          // 0..1023
        int r = idx >> 4;
        int c4 = (idx & 15) * 4;
        bool hasm = (c > 0) || (r > 0);
        bool hasp = (c * 64 + r) < (LSEQ - 1);
        const float* p0 = xraw + rowbase + (size_t)r * CD + h * 64 + c4;
        #pragma unroll
        for (int g = 0; g < 3; g++) {
            const float* pg = p0 + g * D_MODEL;
            float4 rm = hasm ? *(const float4*)(pg - CD) : make_float4(0, 0, 0, 0);
            float4 r0 = *(const float4*)(pg);
            float4 rp = hasp ? *(const float4*)(pg + CD) : make_float4(0, 0, 0, 0);
            int wi = g * 64 + c4;
            float4 o;
            o.x = silu(fmaf(w0s[wi + 0], rm.x, fmaf(w1s[wi + 0], r0.x, fmaf(w2s[wi + 0], rp.x, bss[wi + 0]))));
            o.y = silu(fmaf(w0s[wi + 1], rm.y, fmaf(w1s[wi + 1], r0.y, fmaf(w2s[wi + 1], rp.y, bss[wi + 1]))));
            o.z = silu(fmaf(w0s[wi + 2], rm.z, fmaf(w1s[wi + 2], r0.z, fmaf(w2s[wi + 2], rp.z, bss[wi + 2]))));
            o.w = silu(fmaf(w0s[wi + 3], rm.w, fmaf(w1s[wi + 3], r0.w, fmaf(w2s[wi + 3], rp.w, bss[wi + 3]))));
            if (g == 0)      { *(float4*)&xs[r][c4] = o; }
            else if (g == 1) { Bs[r][c4] = o.x; Bs[r][c4+1] = o.y; Bs[r][c4+2] = o.z; Bs[r][c4+3] = o.w; }
            else             { Cs[r][c4] = o.x; Cs[r][c4+1] = o.y; Cs[r][c4+2] = o.z; Cs[r][c4+3] = o.w; }
        }
    }
    __syncthreads();

    // stage 1: G[l,m] (4x4 per thread) + off[l]
    int lb = tid >> 4;
    int mb = tid & 15;
    float g4[4][4];
    #pragma unroll
    for (int i = 0; i < 4; i++)
        #pragma unroll
        for (int j = 0; j < 4; j++) g4[i][j] = 0.f;
    for (int n = 0; n < 64; n++) {
        float cr[4], br[4];
        #pragma unroll
        for (int i = 0; i < 4; i++) cr[i] = Cs[lb * 4 + i][n];
        #pragma unroll
        for (int j = 0; j < 4; j++) br[j] = Bs[mb * 4 + j][n];
        #pragma unroll
        for (int i = 0; i < 4; i++)
            #pragma unroll
            for (int j = 0; j < 4; j++) g4[i][j] = fmaf(cr[i], br[j], g4[i][j]);
    }
    if (tid < 64) {
        float o = 0.f;
        for (int n = 0; n < 64; n++) o = fmaf(pv[n], Cs[tid][n], o);
        off[tid] = o;
    }
    __syncthreads();
    #pragma unroll
    for (int i = 0; i < 4; i++)
        #pragma unroll
        for (int j = 0; j < 4; j++) {
            int l = lb * 4 + i, m = mb * 4 + j;
            Bs[l][m] = (m <= l) ? g4[i][j] : 0.f;
        }
    __syncthreads();

    // stage 2: Y[l, pb..pb+15] = sum_m G[l,m]*x[m,p] + off[l]
    int l = tid >> 2;
    int pb = (tid & 3) * 16;
    float acc[16];
    float ofl = off[l];
    #pragma unroll
    for (int i = 0; i < 16; i++) acc[i] = ofl;
    int mmax = l | 3;
    for (int m = 0; m <= mmax; m++) {
        float gv = Bs[l][m];
        float4 x0 = *(const float4*)&xs[m][pb];
        float4 x1 = *(const float4*)&xs[m][pb + 4];
        float4 x2 = *(const float4*)&xs[m][pb + 8];
        float4 x3 = *(const float4*)&xs[m][pb + 12];
        acc[0]  = fmaf(gv, x0.x, acc[0]);  acc[1]  = fmaf(gv, x0.y, acc[1]);
        acc[2]  = fmaf(gv, x0.z, acc[2]);  acc[3]  = fmaf(gv, x0.w, acc[3]);
        acc[4]  = fmaf(gv, x1.x, acc[4]);  acc[5]  = fmaf(gv, x1.y, acc[5]);
        acc[6]  = fmaf(gv, x1.z, acc[6]);  acc[7]  = fmaf(gv, x1.w, acc[7]);
        acc[8]  = fmaf(gv, x2.x, acc[8]);  acc[9]  = fmaf(gv, x2.y, acc[9]);
        acc[10] = fmaf(gv, x2.z, acc[10]); acc[11] = fmaf(gv, x2.w, acc[11]);
        acc[12] = fmaf(gv, x3.x, acc[12]); acc[13] = fmaf(gv, x3.y, acc[13]);
        acc[14] = fmaf(gv, x3.z, acc[14]); acc[15] = fmaf(gv, x3.w, acc[15]);
    }
    float* dst = yraw + ((size_t)(b * LSEQ + c * 64 + l)) * D_MODEL + h * 64 + pb;
    #pragma unroll
    for (int q = 0; q < 4; q++)
        *(float4*)(dst + q * 4) = make_float4(acc[q * 4], acc[q * 4 + 1],
                                              acc[q * 4 + 2], acc[q * 4 + 3]);
}

// ---------------------------------------------------------------------------
// y = y*silu(z); y *= rsqrt(mean(y^2)+eps)*rms_w.  Writes fp16 for gemm2.
// ---------------------------------------------------------------------------
__global__ __launch_bounds__(256) void gate_rms_h(
    const float* __restrict__ ybuf, const float* __restrict__ zbuf,
    const float* __restrict__ rms_w, _Float16* __restrict__ ynh)
{
    int row = blockIdx.x;
    const float* yp = ybuf + (size_t)row * D_MODEL;
    const float* zp = zbuf + (size_t)row * D_MODEL;
    float v[8];
    float ss = 0.f;
    #pragma unroll
    for (int j = 0; j < 8; j++) {
        int col = threadIdx.x + 256 * j;
        float y = yp[col];
        float z = zp[col];
        float gv = y * silu(z);
        v[j] = gv;
        ss = fmaf(gv, gv, ss);
    }
    #pragma unroll
    for (int o = 32; o > 0; o >>= 1) ss += __shfl_xor(ss, o);
    __shared__ float red[4];
    int wid = threadIdx.x >> 6;
    if ((threadIdx.x & 63) == 0) red[wid] = ss;
    __syncthreads();
    float tot = red[0] + red[1] + red[2] + red[3];
    float scale = rsqrtf(tot * (1.f / D_MODEL) + RMS_EPS);
    _Float16* op = ynh + (size_t)row * D_MODEL;
    #pragma unroll
    for (int j = 0; j < 8; j++) {
        int col = threadIdx.x + 256 * j;
        op[col] = (_Float16)(v[j] * scale * rms_w[col]);
    }
}

// ---------------------------------------------------------------------------
extern "C" void kernel_launch(void* const* d_in, const int* in_sizes, int n_in,
                              void* d_out, int out_size, void* d_ws, size_t ws_size,
                              hipStream_t stream)
{
    const float* u      = (const float*)d_in[0];
    const float* W_in   = (const float*)d_in[1];
    const float* W_out  = (const float*)d_in[2];
    const float* conv_w = (const float*)d_in[3];
    const float* conv_b = (const float*)d_in[4];
    const float* A_log  = (const float*)d_in[5];
    const float* rms_w  = (const float*)d_in[6];
    float* out = (float*)d_out;

    // workspace (fp32 elems): xraw 50.3M | ybuf 16.8M | cs 0.26M | prev 0.26M
    // = 258 MB.  Overlays: uh+wh (16.8M halfs each) live in ybuf's region
    // until gemm1; woh+ynh live in xraw's region after ssd_y.  z in d_out.
    float* xraw  = (float*)d_ws;
    float* ybuf  = xraw + (size_t)NROWS * CONV_DIM;
    float* csbuf = ybuf + (size_t)NROWS * D_MODEL;
    float* prevb = csbuf + 262144;
    float* zbuf  = out;

    _Float16* uh  = (_Float16*)ybuf;                       // 32 MB
    _Float16* wh  = uh + (size_t)NROWS * D_MODEL;          // 32 MB
    _Float16* woh = (_Float16*)xraw;                       // 8 MB
    _Float16* ynh = woh + (size_t)D_MODEL * D_MODEL;       // 32 MB

    // 1) fp16 casts of gemm1 operands (uh/wh die before ybuf is written)
    cvt_f16<<<dim3(8192), 256, 0, stream>>>(u, uh);
    cvt_f16<<<dim3(8192), 256, 0, stream>>>(W_in, wh);   // first 8192 rows only
    // 2) zxbcdt = u @ W_in^T : z -> d_out, xBC -> xraw
    gemm_f16<<<dim3(64, 64), 256, 0, stream>>>(uh, wh, zbuf, xraw,
                                               NROWS, 8192, D_MODEL,
                                               D_MODEL, D_MODEL, CONV_DIM);
    // 3) chunk states (conv fused)
    cs_conv<<<dim3(4096), 64, 0, stream>>>(xraw, conv_w, conv_b, csbuf);
    // 4) inter-chunk scan
    scan_kernel<<<dim3(64), 64, 0, stream>>>(csbuf, A_log, prevb);
    // 5) per-chunk Y (conv fused)
    ssd_y<<<dim3(4096), 256, 0, stream>>>(xraw, conv_w, conv_b, prevb, ybuf);
    // 6) casts for gemm2 (xraw dead now)
    cvt_f16<<<dim3(2048), 256, 0, stream>>>(W_out, woh);
    // 7) gate + RMSNorm -> fp16
    gate_rms_h<<<dim3(NROWS), 256, 0, stream>>>(ybuf, zbuf, rms_w, ynh);
    // 8) out = ynorm @ W_out^T
    gemm_f16<<<dim3(16, 64), 256, 0, stream>>>(ynh, woh, out, out,
                                               NROWS, D_MODEL, D_MODEL,
                                               D_MODEL, D_MODEL, D_MODEL);
}

// Round 7
// 777.650 us; speedup vs baseline: 5.6654x; 1.0873x over previous
//
#include <hip/hip_runtime.h>
#include <math.h>

#define D_MODEL 2048
#define CONV_DIM 6144
#define N_HEADS 32
#define LSEQ 4096
#define NROWS 8192           // B*L
#define NCHUNK 64
#define RMS_EPS 1.1920929e-07f

#define GK 2048              // K of both GEMMs (compile-time)
#define KTILES 32            // GK / 64

typedef _Float16 half8 __attribute__((ext_vector_type(8)));
typedef float f32x4 __attribute__((ext_vector_type(4)));

__device__ __forceinline__ float silu(float v) { return v / (1.f + expf(-v)); }

__device__ __forceinline__ void glds16(const void* g, void* l) {
    __builtin_amdgcn_global_load_lds((const __attribute__((address_space(1))) void*)g,
                                     (__attribute__((address_space(3))) void*)l,
                                     16, 0, 0);
}

// ---------------------------------------------------------------------------
// fp32 -> fp16 cast, 8 elements/thread.
// ---------------------------------------------------------------------------
__global__ __launch_bounds__(256) void cvt_f16(
    const float* __restrict__ src, _Float16* __restrict__ dst)
{
    size_t i = ((size_t)blockIdx.x * 256 + threadIdx.x) * 8;
    float4 f0 = *(const float4*)(src + i);
    float4 f1 = *(const float4*)(src + i + 4);
    half8 h;
    h[0] = (_Float16)f0.x; h[1] = (_Float16)f0.y;
    h[2] = (_Float16)f0.z; h[3] = (_Float16)f0.w;
    h[4] = (_Float16)f1.x; h[5] = (_Float16)f1.y;
    h[6] = (_Float16)f1.z; h[7] = (_Float16)f1.w;
    *(half8*)(dst + i) = h;
}

// ---------------------------------------------------------------------------
// fp16 NT MFMA GEMM, 256x256 tile, BK=64, 8 waves (512 thr), phase-split
// schedule with counted vmcnt (T2+T3+T4+T5).  K fixed at GK=2048.
// LDS: 2 x [256 rows][64 k] per operand, fp16, 128 KiB total.
//   phys 16B-slot = logical k16 ^ (row & 7)  (write-side pre-swizzled source,
//   read-side swizzled ds_read -> 2-way conflicts only).
// Staging: all 8 global_load_lds for tile t+1 issued at phase 0 of tile t;
//   waited with vmcnt(8) (tile t's 8 oldest) -> loads span a full tile of MFMA.
// Output cols < nsplit -> C0 (ld ldc0), else C1 (ld ldc1, col-nsplit).
// ---------------------------------------------------------------------------
__global__ __launch_bounds__(512, 1) void gemm_f16_256(
    const _Float16* __restrict__ A, const _Float16* __restrict__ B,
    float* __restrict__ C0, float* __restrict__ C1,
    int Mtiles, int Ntiles, int nsplit, int ldc0, int ldc1)
{
    __shared__ __align__(16) _Float16 Al[2][256 * 64];   // 64 KB
    __shared__ __align__(16) _Float16 Bl[2][256 * 64];   // 64 KB

    const int tid  = threadIdx.x;
    const int wid  = tid >> 6;
    const int lane = tid & 63;

    // XCD-aware bijective swizzle (nwg % 8 == 0 for both call sites)
    const int nwg = Mtiles * Ntiles;
    const int cpx = nwg >> 3;
    const int sw  = (blockIdx.x & 7) * cpx + (blockIdx.x >> 3);
    const int bm  = sw / Ntiles, bn = sw % Ntiles;
    const size_t m0 = (size_t)bm * 256, n0 = (size_t)bn * 256;

    // --- staging source (per-lane, pre-swizzled k16): call chunk c covers
    // rows c*64 + (tid>>3); phys slot tid&7 holds logical k16 = (tid&7)^(srow&7).
    const int srow = tid >> 3;
    const int sk16 = (tid & 7) ^ (srow & 7);
    const _Float16* gA = A + (m0 + srow) * GK + sk16 * 8;
    const _Float16* gB = B + (n0 + srow) * GK + sk16 * 8;

    // --- fragment read constants.  A-frag row R = wm*128+mh*64+i*16+(lane&15):
    // R&7 == lane&7, so swizzle XOR is lane&7 for every fragment.
    const int wm = wid >> 2, wn = wid & 3;
    const int rowA = (wm * 128 + (lane & 15)) * 128;          // byte
    const int rowB = (wn * 64 + (lane & 15)) * 128;           // byte
    const int slotx0 = (((0 * 4 + (lane >> 4)) ^ (lane & 7)) << 4);
    const int slotx1 = (((1 * 4 + (lane >> 4)) ^ (lane & 7)) << 4);

    f32x4 acc[8][4];
    #pragma unroll
    for (int i = 0; i < 8; i++)
        #pragma unroll
        for (int j = 0; j < 4; j++) acc[i][j] = (f32x4)0.f;
    half8 bf0, bf1, bf2, bf3;

#define STAGE(bufsel, tt) do {                                              \
    const _Float16* _ga = gA + (size_t)(tt) * 64;                           \
    const _Float16* _gb = gB + (size_t)(tt) * 64;                           \
    char* _la = (char*)&Al[(bufsel)][0] + wid * 1024;                       \
    char* _lb = (char*)&Bl[(bufsel)][0] + wid * 1024;                       \
    glds16(_ga,               _la);                                         \
    glds16(_ga + 1 * 64 * GK, _la + 1 * 8192);                              \
    glds16(_ga + 2 * 64 * GK, _la + 2 * 8192);                              \
    glds16(_ga + 3 * 64 * GK, _la + 3 * 8192);                              \
    glds16(_gb,               _lb);                                         \
    glds16(_gb + 1 * 64 * GK, _lb + 1 * 8192);                              \
    glds16(_gb + 2 * 64 * GK, _lb + 2 * 8192);                              \
    glds16(_gb + 3 * 64 * GK, _lb + 3 * 8192);                              \
} while (0)

#define MFMA16(mh)                                                          \
    __builtin_amdgcn_s_setprio(1);                                          \
    acc[(mh)*4+0][0] = __builtin_amdgcn_mfma_f32_16x16x32_f16(af0, bf0, acc[(mh)*4+0][0], 0, 0, 0); \
    acc[(mh)*4+0][1] = __builtin_amdgcn_mfma_f32_16x16x32_f16(af0, bf1, acc[(mh)*4+0][1], 0, 0, 0); \
    acc[(mh)*4+0][2] = __builtin_amdgcn_mfma_f32_16x16x32_f16(af0, bf2, acc[(mh)*4+0][2], 0, 0, 0); \
    acc[(mh)*4+0][3] = __builtin_amdgcn_mfma_f32_16x16x32_f16(af0, bf3, acc[(mh)*4+0][3], 0, 0, 0); \
    acc[(mh)*4+1][0] = __builtin_amdgcn_mfma_f32_16x16x32_f16(af1, bf0, acc[(mh)*4+1][0], 0, 0, 0); \
    acc[(mh)*4+1][1] = __builtin_amdgcn_mfma_f32_16x16x32_f16(af1, bf1, acc[(mh)*4+1][1], 0, 0, 0); \
    acc[(mh)*4+1][2] = __builtin_amdgcn_mfma_f32_16x16x32_f16(af1, bf2, acc[(mh)*4+1][2], 0, 0, 0); \
    acc[(mh)*4+1][3] = __builtin_amdgcn_mfma_f32_16x16x32_f16(af1, bf3, acc[(mh)*4+1][3], 0, 0, 0); \
    acc[(mh)*4+2][0] = __builtin_amdgcn_mfma_f32_16x16x32_f16(af2, bf0, acc[(mh)*4+2][0], 0, 0, 0); \
    acc[(mh)*4+2][1] = __builtin_amdgcn_mfma_f32_16x16x32_f16(af2, bf1, acc[(mh)*4+2][1], 0, 0, 0); \
    acc[(mh)*4+2][2] = __builtin_amdgcn_mfma_f32_16x16x32_f16(af2, bf2, acc[(mh)*4+2][2], 0, 0, 0); \
    acc[(mh)*4+2][3] = __builtin_amdgcn_mfma_f32_16x16x32_f16(af2, bf3, acc[(mh)*4+2][3], 0, 0, 0); \
    acc[(mh)*4+3][0] = __builtin_amdgcn_mfma_f32_16x16x32_f16(af3, bf0, acc[(mh)*4+3][0], 0, 0, 0); \
    acc[(mh)*4+3][1] = __builtin_amdgcn_mfma_f32_16x16x32_f16(af3, bf1, acc[(mh)*4+3][1], 0, 0, 0); \
    acc[(mh)*4+3][2] = __builtin_amdgcn_mfma_f32_16x16x32_f16(af3, bf2, acc[(mh)*4+3][2], 0, 0, 0); \
    acc[(mh)*4+3][3] = __builtin_amdgcn_mfma_f32_16x16x32_f16(af3, bf3, acc[(mh)*4+3][3], 0, 0, 0); \
    __builtin_amdgcn_s_setprio(0);

#define LOADA(bufsel, mh, SLX)                                              \
    half8 af0 = *(const half8*)((const char*)&Al[(bufsel)][0] + rowA + ((mh)*64+ 0)*128 + (SLX)); \
    half8 af1 = *(const half8*)((const char*)&Al[(bufsel)][0] + rowA + ((mh)*64+16)*128 + (SLX)); \
    half8 af2 = *(const half8*)((const char*)&Al[(bufsel)][0] + rowA + ((mh)*64+32)*128 + (SLX)); \
    half8 af3 = *(const half8*)((const char*)&Al[(bufsel)][0] + rowA + ((mh)*64+48)*128 + (SLX));

#define LOADB(bufsel, SLX)                                                  \
    bf0 = *(const half8*)((const char*)&Bl[(bufsel)][0] + rowB +    0 + (SLX)); \
    bf1 = *(const half8*)((const char*)&Bl[(bufsel)][0] + rowB + 2048 + (SLX)); \
    bf2 = *(const half8*)((const char*)&Bl[(bufsel)][0] + rowB + 4096 + (SLX)); \
    bf3 = *(const half8*)((const char*)&Bl[(bufsel)][0] + rowB + 6144 + (SLX));

    // prologue: stage tile 0 into buf 0
    STAGE(0, 0);

    for (int t = 0; t < KTILES; ++t) {
        const int cur = t & 1;
        // ---- phase 0: issue next tile's staging, counted wait, barrier.
        if (t + 1 < KTILES) {
            STAGE(cur ^ 1, t + 1);
            __builtin_amdgcn_sched_barrier(0);
            asm volatile("s_waitcnt vmcnt(8)" ::: "memory");
        } else {
            asm volatile("s_waitcnt vmcnt(0)" ::: "memory");
        }
        __builtin_amdgcn_sched_barrier(0);
        __builtin_amdgcn_s_barrier();     // all waves certified tile t in LDS
        {
            LOADA(cur, 0, slotx0)
            LOADB(cur, slotx0)
            MFMA16(0)
            __builtin_amdgcn_s_barrier();
        }
        // ---- phase 1: (mh1, ks0), reuse bf
        {
            LOADA(cur, 1, slotx0)
            __builtin_amdgcn_s_barrier();
            MFMA16(1)
            __builtin_amdgcn_s_barrier();
        }
        // ---- phase 2: (mh0, ks1), reload bf
        {
            LOADA(cur, 0, slotx1)
            LOADB(cur, slotx1)
            __builtin_amdgcn_s_barrier();
            MFMA16(0)
            __builtin_amdgcn_s_barrier();
        }
        // ---- phase 3: (mh1, ks1)
        {
            LOADA(cur, 1, slotx1)
            __builtin_amdgcn_s_barrier();
            MFMA16(1)
            __builtin_amdgcn_s_barrier();
        }
    }

    // ---- epilogue: D mapping col=lane&15, row=(lane>>4)*4+j
    const int crow = (lane >> 4) * 4;
    const int ccol = lane & 15;
    #pragma unroll
    for (int mt = 0; mt < 8; mt++) {
        #pragma unroll
        for (int nt = 0; nt < 4; nt++) {
            int col  = (int)n0 + wn * 64 + nt * 16 + ccol;
            int rowb = (int)m0 + wm * 128 + mt * 16 + crow;
            #pragma unroll
            for (int j = 0; j < 4; j++) {
                float v = acc[mt][nt][j];
                if (col < nsplit) C0[(size_t)(rowb + j) * ldc0 + col] = v;
                else              C1[(size_t)(rowb + j) * ldc1 + (col - nsplit)] = v;
            }
        }
    }
#undef STAGE
#undef MFMA16
#undef LOADA
#undef LOADB
}

// ---------------------------------------------------------------------------
// chunk_states with conv+silu fused (reads PRE-conv xraw).
// ---------------------------------------------------------------------------
__global__ __launch_bounds__(64) void cs_conv(
    const float* __restrict__ xraw, const float* __restrict__ cw,
    const float* __restrict__ cb, float* __restrict__ cs)
{
    const int CD = CONV_DIM;
    int blk = blockIdx.x;
    int c = blk & 63; int h = (blk >> 6) & 31; int b = blk >> 11;
    int n = threadIdx.x;
    int colx = h * 64 + n;
    int colB = D_MODEL + colx;
    const float* px = xraw + ((size_t)(b * LSEQ + c * 64)) * CD + colx;
    const float* pB = px + D_MODEL;
    float wx0 = cw[colx * 3], wx1 = cw[colx * 3 + 1], wx2 = cw[colx * 3 + 2], bx = cb[colx];
    float wb0 = cw[colB * 3], wb1 = cw[colB * 3 + 1], wb2 = cw[colB * 3 + 2], bb = cb[colB];

    float xm = (c > 0) ? px[-CD] : 0.f;
    float Bm = (c > 0) ? pB[-CD] : 0.f;
    float x0 = px[0], B0 = pB[0];
    float s = 0.f;
    for (int l = 0; l < 64; l++) {
        bool hasp = (c * 64 + l) < (LSEQ - 1);
        float xp = hasp ? px[(size_t)(l + 1) * CD] : 0.f;
        float Bp = hasp ? pB[(size_t)(l + 1) * CD] : 0.f;
        float vx = fmaf(wx0, xm, fmaf(wx1, x0, fmaf(wx2, xp, bx)));
        float vB = fmaf(wb0, Bm, fmaf(wb1, B0, fmaf(wb2, Bp, bb)));
        vx = silu(vx); vB = silu(vB);
        s = fmaf(vx, vB, s);
        xm = x0; x0 = xp; Bm = B0; B0 = Bp;
    }
    cs[(size_t)blk * 64 + n] = s;
}

// ---------------------------------------------------------------------------
// Sequential chunk scan.  decay = exp(63*A_log[h]).
// ---------------------------------------------------------------------------
__global__ void scan_kernel(const float* __restrict__ cs,
                            const float* __restrict__ A_log,
                            float* __restrict__ prev)
{
    int bh = blockIdx.x;
    int h = bh & 31;
    int n = threadIdx.x;
    float d = expf(63.f * A_log[h]);
    float st = 0.f;
    for (int c = 0; c < NCHUNK; c++) {
        size_t i = ((size_t)bh * 64 + c) * 64 + n;
        prev[i] = st;
        st = fmaf(st, d, cs[i]);
    }
}

// ---------------------------------------------------------------------------
// Per (b,h,chunk): conv+silu on the fly into LDS, then
// G = tril(C B^T); Y = G x + (prev . C[l]) broadcast over p.  256 threads.
// ---------------------------------------------------------------------------
__global__ __launch_bounds__(256) void ssd_y(
    const float* __restrict__ xraw, const float* __restrict__ cw,
    const float* __restrict__ cb, const float* __restrict__ prev,
    float* __restrict__ yraw)
{
    const int CD = CONV_DIM;
    __shared__ float Cs[64][65];
    __shared__ float Bs[64][65];      // holds B, then reused for G
    __shared__ float xs[64][64];
    __shared__ float pv[64];
    __shared__ float off[64];
    __shared__ float w0s[192], w1s[192], w2s[192], bss[192];

    int blk = blockIdx.x;
    int c = blk & 63; int h = (blk >> 6) & 31; int b = blk >> 11;
    int tid = threadIdx.x;

    if (tid < 192) {
        int g = tid >> 6, n = tid & 63;
        int col = g * D_MODEL + h * 64 + n;
        w0s[tid] = cw[col * 3]; w1s[tid] = cw[col * 3 + 1]; w2s[tid] = cw[col * 3 + 2];
        bss[tid] = cb[col];
    }
    if (tid < 64) pv[tid] = prev[((size_t)(b * 32 + h) * 64 + c) * 64 + tid];
    __syncthreads();

    size_t rowbase = ((size_t)(b * LSEQ + c * 64)) * CD;
    #pragma unroll
    for (int j = 0; j < 4; j++) {
        int idx = tid + 256 * j;          // 0..1023
        int r = idx >> 4;
        int c4 = (idx & 15) * 4;
        bool hasm = (c > 0) || (r > 0);
        bool hasp = (c * 64 + r) < (LSEQ - 1);
        const float* p0 = xraw + rowbase + (size_t)r * CD + h * 64 + c4;
        #pragma unroll
        for (int g = 0; g < 3; g++) {
            const float* pg = p0 + g * D_MODEL;
            float4 rm = hasm ? *(const float4*)(pg - CD) : make_float4(0, 0, 0, 0);
            float4 r0 = *(const float4*)(pg);
            float4 rp = hasp ? *(const float4*)(pg + CD) : make_float4(0, 0, 0, 0);
            int wi = g * 64 + c4;
            float4 o;
            o.x = silu(fmaf(w0s[wi + 0], rm.x, fmaf(w1s[wi + 0], r0.x, fmaf(w2s[wi + 0], rp.x, bss[wi + 0]))));
            o.y = silu(fmaf(w0s[wi + 1], rm.y, fmaf(w1s[wi + 1], r0.y, fmaf(w2s[wi + 1], rp.y, bss[wi + 1]))));
            o.z = silu(fmaf(w0s[wi + 2], rm.z, fmaf(w1s[wi + 2], r0.z, fmaf(w2s[wi + 2], rp.z, bss[wi + 2]))));
            o.w = silu(fmaf(w0s[wi + 3], rm.w, fmaf(w1s[wi + 3], r0.w, fmaf(w2s[wi + 3], rp.w, bss[wi + 3]))));
            if (g == 0)      { *(float4*)&xs[r][c4] = o; }
            else if (g == 1) { Bs[r][c4] = o.x; Bs[r][c4+1] = o.y; Bs[r][c4+2] = o.z; Bs[r][c4+3] = o.w; }
            else             { Cs[r][c4] = o.x; Cs[r][c4+1] = o.y; Cs[r][c4+2] = o.z; Cs[r][c4+3] = o.w; }
        }
    }
    __syncthreads();

    // stage 1: G[l,m] (4x4 per thread) + off[l]
    int lb = tid >> 4;
    int mb = tid & 15;
    float g4[4][4];
    #pragma unroll
    for (int i = 0; i < 4; i++)
        #pragma unroll
        for (int j = 0; j < 4; j++) g4[i][j] = 0.f;
    for (int n = 0; n < 64; n++) {
        float cr[4], br[4];
        #pragma unroll
        for (int i = 0; i < 4; i++) cr[i] = Cs[lb * 4 + i][n];
        #pragma unroll
        for (int j = 0; j < 4; j++) br[j] = Bs[mb * 4 + j][n];
        #pragma unroll
        for (int i = 0; i < 4; i++)
            #pragma unroll
            for (int j = 0; j < 4; j++) g4[i][j] = fmaf(cr[i], br[j], g4[i][j]);
    }
    if (tid < 64) {
        float o = 0.f;
        for (int n = 0; n < 64; n++) o = fmaf(pv[n], Cs[tid][n], o);
        off[tid] = o;
    }
    __syncthreads();
    #pragma unroll
    for (int i = 0; i < 4; i++)
        #pragma unroll
        for (int j = 0; j < 4; j++) {
            int l = lb * 4 + i, m = mb * 4 + j;
            Bs[l][m] = (m <= l) ? g4[i][j] : 0.f;
        }
    __syncthreads();

    // stage 2: Y[l, pb..pb+15] = sum_m G[l,m]*x[m,p] + off[l]
    int l = tid >> 2;
    int pb = (tid & 3) * 16;
    float acc[16];
    float ofl = off[l];
    #pragma unroll
    for (int i = 0; i < 16; i++) acc[i] = ofl;
    int mmax = l | 3;
    for (int m = 0; m <= mmax; m++) {
        float gv = Bs[l][m];
        float4 x0 = *(const float4*)&xs[m][pb];
        float4 x1 = *(const float4*)&xs[m][pb + 4];
        float4 x2 = *(const float4*)&xs[m][pb + 8];
        float4 x3 = *(const float4*)&xs[m][pb + 12];
        acc[0]  = fmaf(gv, x0.x, acc[0]);  acc[1]  = fmaf(gv, x0.y, acc[1]);
        acc[2]  = fmaf(gv, x0.z, acc[2]);  acc[3]  = fmaf(gv, x0.w, acc[3]);
        acc[4]  = fmaf(gv, x1.x, acc[4]);  acc[5]  = fmaf(gv, x1.y, acc[5]);
        acc[6]  = fmaf(gv, x1.z, acc[6]);  acc[7]  = fmaf(gv, x1.w, acc[7]);
        acc[8]  = fmaf(gv, x2.x, acc[8]);  acc[9]  = fmaf(gv, x2.y, acc[9]);
        acc[10] = fmaf(gv, x2.z, acc[10]); acc[11] = fmaf(gv, x2.w, acc[11]);
        acc[12] = fmaf(gv, x3.x, acc[12]); acc[13] = fmaf(gv, x3.y, acc[13]);
        acc[14] = fmaf(gv, x3.z, acc[14]); acc[15] = fmaf(gv, x3.w, acc[15]);
    }
    float* dst = yraw + ((size_t)(b * LSEQ + c * 64 + l)) * D_MODEL + h * 64 + pb;
    #pragma unroll
    for (int q = 0; q < 4; q++)
        *(float4*)(dst + q * 4) = make_float4(acc[q * 4], acc[q * 4 + 1],
                                              acc[q * 4 + 2], acc[q * 4 + 3]);
}

// ---------------------------------------------------------------------------
// y = y*silu(z); y *= rsqrt(mean(y^2)+eps)*rms_w.  Writes fp16 for gemm2.
// ---------------------------------------------------------------------------
__global__ __launch_bounds__(256) void gate_rms_h(
    const float* __restrict__ ybuf, const float* __restrict__ zbuf,
    const float* __restrict__ rms_w, _Float16* __restrict__ ynh)
{
    int row = blockIdx.x;
    const float* yp = ybuf + (size_t)row * D_MODEL;
    const float* zp = zbuf + (size_t)row * D_MODEL;
    float v[8];
    float ss = 0.f;
    #pragma unroll
    for (int j = 0; j < 8; j++) {
        int col = threadIdx.x + 256 * j;
        float y = yp[col];
        float z = zp[col];
        float gv = y * silu(z);
        v[j] = gv;
        ss = fmaf(gv, gv, ss);
    }
    #pragma unroll
    for (int o = 32; o > 0; o >>= 1) ss += __shfl_xor(ss, o);
    __shared__ float red[4];
    int wid = threadIdx.x >> 6;
    if ((threadIdx.x & 63) == 0) red[wid] = ss;
    __syncthreads();
    float tot = red[0] + red[1] + red[2] + red[3];
    float scale = rsqrtf(tot * (1.f / D_MODEL) + RMS_EPS);
    _Float16* op = ynh + (size_t)row * D_MODEL;
    #pragma unroll
    for (int j = 0; j < 8; j++) {
        int col = threadIdx.x + 256 * j;
        op[col] = (_Float16)(v[j] * scale * rms_w[col]);
    }
}

// ---------------------------------------------------------------------------
extern "C" void kernel_launch(void* const* d_in, const int* in_sizes, int n_in,
                              void* d_out, int out_size, void* d_ws, size_t ws_size,
                              hipStream_t stream)
{
    const float* u      = (const float*)d_in[0];
    const float* W_in   = (const float*)d_in[1];
    const float* W_out  = (const float*)d_in[2];
    const float* conv_w = (const float*)d_in[3];
    const float* conv_b = (const float*)d_in[4];
    const float* A_log  = (const float*)d_in[5];
    const float* rms_w  = (const float*)d_in[6];
    float* out = (float*)d_out;

    // workspace (fp32 elems): xraw 50.3M | ybuf 16.8M | cs 0.26M | prev 0.26M
    // = 258 MB.  Overlays: uh+wh in ybuf's region until gemm1; woh+ynh in
    // xraw's region after ssd_y.  z lives in d_out until gemm2.
    float* xraw  = (float*)d_ws;
    float* ybuf  = xraw + (size_t)NROWS * CONV_DIM;
    float* csbuf = ybuf + (size_t)NROWS * D_MODEL;
    float* prevb = csbuf + 262144;
    float* zbuf  = out;

    _Float16* uh  = (_Float16*)ybuf;                       // 32 MB
    _Float16* wh  = uh + (size_t)NROWS * D_MODEL;          // 32 MB
    _Float16* woh = (_Float16*)xraw;                       // 8 MB
    _Float16* ynh = woh + (size_t)D_MODEL * D_MODEL;       // 32 MB

    // 1) fp16 casts of gemm1 operands
    cvt_f16<<<dim3(8192), 256, 0, stream>>>(u, uh);
    cvt_f16<<<dim3(8192), 256, 0, stream>>>(W_in, wh);   // first 8192 rows only
    // 2) zxbcdt = u @ W_in^T : z -> d_out, xBC -> xraw
    gemm_f16_256<<<dim3(1024), 512, 0, stream>>>(uh, wh, zbuf, xraw,
                                                 32, 32, D_MODEL, D_MODEL, CONV_DIM);
    // 3) chunk states (conv fused)
    cs_conv<<<dim3(4096), 64, 0, stream>>>(xraw, conv_w, conv_b, csbuf);
    // 4) inter-chunk scan
    scan_kernel<<<dim3(64), 64, 0, stream>>>(csbuf, A_log, prevb);
    // 5) per-chunk Y (conv fused)
    ssd_y<<<dim3(4096), 256, 0, stream>>>(xraw, conv_w, conv_b, prevb, ybuf);
    // 6) cast W_out (xraw dead now)
    cvt_f16<<<dim3(2048), 256, 0, stream>>>(W_out, woh);
    // 7) gate + RMSNorm -> fp16
    gate_rms_h<<<dim3(NROWS), 256, 0, stream>>>(ybuf, zbuf, rms_w, ynh);
    // 8) out = ynorm @ W_out^T
    gemm_f16_256<<<dim3(256), 512, 0, stream>>>(ynh, woh, out, out,
                                                32, 8, D_MODEL, D_MODEL, D_MODEL);
}